// Round 4
// baseline (397.853 us; speedup 1.0000x reference)
//
#include <hip/hip_runtime.h>

#define N_NODES 40000
#define N_EDGES 640000
#define NFEAT   128
#define N_GRAPHS 512
#define SCAN_NB 157        // ceil(40000/256)
#define NSLICES 8          // 128 / 16
#define SLICE_BLOCKS 2500  // 40000 nodes / 16 nodes-per-block
#define EPAD_MAX (N_EDGES + 3 * N_NODES)   // worst-case padded CSR

// ===========================================================================
// CSR build kernels (padded to multiple-of-4 lists, sentinel row = N_NODES)
// ===========================================================================

__global__ void edge_deg_int_kernel(const int* __restrict__ ei, int* __restrict__ degcnt, int E) {
    int e = blockIdx.x * blockDim.x + threadIdx.x;
    if (e < E) atomicAdd(&degcnt[ei[E + e]], 1);
}

__global__ void batch_hist_kernel(const int* __restrict__ batch, int* __restrict__ gcnt, int n) {
    int i = blockIdx.x * blockDim.x + threadIdx.x;
    if (i < n) atomicAdd(&gcnt[batch[i]], 1);
}

// kept for tier C
__global__ void dinv_from_int_kernel(const int* __restrict__ degcnt, float* __restrict__ dinv, int n) {
    int i = blockIdx.x * blockDim.x + threadIdx.x;
    if (i < n) dinv[i] = rsqrtf(1.0f + (float)degcnt[i]);
}

// scan PADDED degrees ((deg+3)&~3); also emit dinv = rsqrt(1+deg)
__global__ void scan1_kernel(const int* __restrict__ in, int* __restrict__ out,
                             int* __restrict__ bsums, float* __restrict__ dinv, int n) {
    __shared__ int tmp[256];
    int t = threadIdx.x;
    int i = blockIdx.x * 256 + t;
    int deg = (i < n) ? in[i] : 0;
    if (i < n) dinv[i] = rsqrtf(1.0f + (float)deg);
    int vp = (i < n) ? ((deg + 3) & ~3) : 0;
    tmp[t] = vp;
    __syncthreads();
    for (int off = 1; off < 256; off <<= 1) {
        int add = (t >= off) ? tmp[t - off] : 0;
        __syncthreads();
        tmp[t] += add;
        __syncthreads();
    }
    if (i < n) out[i] = tmp[t] - vp;
    if (t == 255) bsums[blockIdx.x] = tmp[255];
}

__global__ void scan2_kernel(int* __restrict__ bsums, int nb) {
    __shared__ int tmp[256];
    int t = threadIdx.x;
    int v = (t < nb) ? bsums[t] : 0;
    tmp[t] = v;
    __syncthreads();
    for (int off = 1; off < 256; off <<= 1) {
        int add = (t >= off) ? tmp[t - off] : 0;
        __syncthreads();
        tmp[t] += add;
        __syncthreads();
    }
    if (t < nb) bsums[t] = tmp[t] - v;
}

__global__ void scan3_kernel(int* __restrict__ rowptr, const int* __restrict__ bsums,
                             int* __restrict__ cursor, const int* __restrict__ degcnt,
                             int n) {
    int i = blockIdx.x * 256 + threadIdx.x;
    if (i < n) {
        int v = rowptr[i] + bsums[blockIdx.x];
        rowptr[i] = v;
        cursor[i] = v;
        if (i == n - 1) rowptr[n] = v + ((degcnt[i] + 3) & ~3);
    }
}

template <typename IdxT>
__global__ void fill_kernel(const int* __restrict__ ei, int* __restrict__ cursor,
                            IdxT* __restrict__ csr, int E) {
    int e = blockIdx.x * blockDim.x + threadIdx.x;
    if (e < E) {
        int c = ei[E + e];
        int p = atomicAdd(&cursor[c], 1);
        csr[p] = (IdxT)ei[e];
    }
}

// fill pad slots [cursor[i], rowptr[i+1]) with sentinel row N_NODES
template <typename IdxT>
__global__ void pad_kernel(const int* __restrict__ rowptr, const int* __restrict__ cursor,
                           IdxT* __restrict__ csr, int n) {
    int i = blockIdx.x * blockDim.x + threadIdx.x;
    if (i < n) {
        int end = rowptr[i + 1];
        for (int p = cursor[i]; p < end; ++p) csr[p] = (IdxT)N_NODES;
    }
}

// out[g] = bfc (atomic accumulation target)
__global__ void out_init_kernel(float* __restrict__ out, const float* __restrict__ bfc, int g) {
    int i = blockIdx.x * blockDim.x + threadIdx.x;
    if (i < g) out[i] = bfc[0];
}

// ===========================================================================
// GEMM: Ht[r][c] = dinv[r] * sum_k X[r][k] * W[k][c]
// 256 threads -> 64 rows x 64 cols; W col-half (32 KB LDS) -> 4 blocks/CU.
// ===========================================================================
__global__ __launch_bounds__(256, 4) void gemm64_kernel(const float* __restrict__ X,
                                                        const float* __restrict__ W,
                                                        const float* __restrict__ dinv,
                                                        float* __restrict__ H) {
    __shared__ float Ws[128 * 64];
    const int colhalf = blockIdx.x & 1;
    const int tile    = blockIdx.x >> 1;

    for (int i = threadIdx.x; i < 2048; i += 256) {
        int k   = i >> 4;
        int cc4 = (i & 15) * 4;
        *(float4*)(Ws + k * 64 + cc4) = *(const float4*)(W + k * 128 + colhalf * 64 + cc4);
    }
    __syncthreads();

    const int rg = threadIdx.x >> 4;
    const int cg = threadIdx.x & 15;
    const int row0 = tile * 64 + rg * 4;
    const float* x0 = X + (size_t)row0 * NFEAT;

    float acc[4][4] = {};
    float4 xc[4], xn[4];
    #pragma unroll
    for (int i = 0; i < 4; i++) xc[i] = *(const float4*)(x0 + (size_t)i * NFEAT);

    #pragma unroll 4
    for (int k = 0; k < 128; k += 4) {
        const int kn = (k + 4) & 127;
        #pragma unroll
        for (int i = 0; i < 4; i++) xn[i] = *(const float4*)(x0 + (size_t)i * NFEAT + kn);

        float4 wv[4];
        #pragma unroll
        for (int m = 0; m < 4; m++) wv[m] = *(const float4*)(Ws + (k + m) * 64 + cg * 4);

        #pragma unroll
        for (int i = 0; i < 4; i++) {
            const float xi[4] = {xc[i].x, xc[i].y, xc[i].z, xc[i].w};
            #pragma unroll
            for (int m = 0; m < 4; m++) {
                acc[i][0] += xi[m] * wv[m].x;
                acc[i][1] += xi[m] * wv[m].y;
                acc[i][2] += xi[m] * wv[m].z;
                acc[i][3] += xi[m] * wv[m].w;
            }
        }
        #pragma unroll
        for (int i = 0; i < 4; i++) xc[i] = xn[i];
    }

    #pragma unroll
    for (int i = 0; i < 4; i++) {
        float dr = dinv[row0 + i];
        float4 o = {acc[i][0] * dr, acc[i][1] * dr, acc[i][2] * dr, acc[i][3] * dr};
        *(float4*)(H + (size_t)(row0 + i) * NFEAT + colhalf * 64 + cg * 4) = o;
    }
}

// ===========================================================================
// Sliced gather: slice = 16 features (64 B) -> per-slice Ht working set 2.5 MB,
// L2-resident on every XCD. Grid = NSLICES * SLICE_BLOCKS, slice-major order.
// 16 lanes per node, 16 nodes per 256-thread block. CSR lists padded to x4 ->
// aligned 4-index vector loads; sentinel row N_NODES is zero.
// FUSE_POOL: instead of writing out rows, dot slice with Wfc and atomically
// accumulate per-node scalar into nodedot.
// ===========================================================================
template <typename IdxT, typename IdxV, bool FUSE_POOL>
__global__ __launch_bounds__(256) void gather_sliced_kernel(
        const int* __restrict__ rowptr, const IdxT* __restrict__ csr,
        const float* __restrict__ dinv, const float* __restrict__ Ht,
        const float* __restrict__ bias, float* __restrict__ out,
        const float* __restrict__ Wfc, float* __restrict__ nodedot) {
    const int slice = blockIdx.x / SLICE_BLOCKS;
    const int nblk  = blockIdx.x % SLICE_BLOCKS;
    const int node  = nblk * 16 + (threadIdx.x >> 4);
    const int lane16 = threadIdx.x & 15;
    const int f = slice * 16 + lane16;

    const int start = rowptr[node];
    const int end   = rowptr[node + 1];

    float acc0 = Ht[(size_t)node * NFEAT + f];   // self-loop
    float acc1 = 0.0f, acc2 = 0.0f, acc3 = 0.0f;

    for (int j = start; j < end; j += 4) {
        IdxV rr = *(const IdxV*)(csr + j);       // aligned: start % 4 == 0
        int r0 = (int)rr.x, r1 = (int)rr.y, r2 = (int)rr.z, r3 = (int)rr.w;
        acc0 += Ht[(size_t)r0 * NFEAT + f];
        acc1 += Ht[(size_t)r1 * NFEAT + f];
        acc2 += Ht[(size_t)r2 * NFEAT + f];
        acc3 += Ht[(size_t)r3 * NFEAT + f];
    }
    float v = ((acc0 + acc1) + (acc2 + acc3)) * dinv[node] + bias[f];
    v = fmaxf(v, 0.0f);

    if (!FUSE_POOL) {
        out[(size_t)node * NFEAT + f] = v;
    } else {
        float d = v * Wfc[f];
        d += __shfl_xor(d, 1, 64);
        d += __shfl_xor(d, 2, 64);
        d += __shfl_xor(d, 4, 64);
        d += __shfl_xor(d, 8, 64);
        if (lane16 == 0) atomicAdd(&nodedot[node], d);
    }
}

// out[batch[i]] += nodedot[i] / cnt
__global__ void pool_final_kernel(const float* __restrict__ nodedot,
                                  const int* __restrict__ batch,
                                  const int* __restrict__ gcnt,
                                  float* __restrict__ out, int n) {
    int i = blockIdx.x * blockDim.x + threadIdx.x;
    if (i < n) {
        int g = batch[i];
        int c = gcnt[g];
        float cf = (float)(c > 0 ? c : 1);
        atomicAdd(&out[g], nodedot[i] / cf);
    }
}

// ===========================================================================
// Tier C fallback kernels (atomic scatter; Ht pre-scaled by dinv[r])
// ===========================================================================
__global__ __launch_bounds__(256) void edge_scatter_kernel(const int* __restrict__ ei,
                                                           const float* __restrict__ dinv,
                                                           const float* __restrict__ H,
                                                           float* __restrict__ agg,
                                                           int E) {
    long long gid = (long long)blockIdx.x * blockDim.x + threadIdx.x;
    int e = (int)(gid >> 5);
    if (e >= E) return;
    int c4 = ((int)gid & 31) * 4;
    int r = ei[e];
    int c = ei[E + e];
    float norm = dinv[c];
    const float4 hv = *(const float4*)(H + (size_t)r * NFEAT + c4);
    float* dst = agg + (size_t)c * NFEAT + c4;
    atomicAdd(dst + 0, hv.x * norm);
    atomicAdd(dst + 1, hv.y * norm);
    atomicAdd(dst + 2, hv.z * norm);
    atomicAdd(dst + 3, hv.w * norm);
}

__global__ void post_kernel(float* __restrict__ agg, const float* __restrict__ H,
                            const float* __restrict__ dinv, const float* __restrict__ b,
                            int n) {
    int gid = blockIdx.x * blockDim.x + threadIdx.x;
    if (gid >= n * 32) return;
    int node = gid >> 5;
    int c4 = (gid & 31) * 4;
    float s = dinv[node];
    float4 a  = *(float4*)(agg + (size_t)gid * 4);
    float4 hv = *(const float4*)(H + (size_t)gid * 4);
    float4 bb = *(const float4*)(b + c4);
    float4 o;
    o.x = fmaxf(a.x + hv.x * s + bb.x, 0.0f);
    o.y = fmaxf(a.y + hv.y * s + bb.y, 0.0f);
    o.z = fmaxf(a.z + hv.z * s + bb.z, 0.0f);
    o.w = fmaxf(a.w + hv.w * s + bb.w, 0.0f);
    *(float4*)(agg + (size_t)gid * 4) = o;
}

__global__ __launch_bounds__(128) void pool_fc_kernel(const float* __restrict__ H,
                                                      const int* __restrict__ batch,
                                                      const float* __restrict__ Wfc,
                                                      const float* __restrict__ bfc,
                                                      float* __restrict__ out, int n) {
    int g = blockIdx.x;
    int tid = threadIdx.x;
    int lo = 0, hi = n;
    while (lo < hi) { int mid = (lo + hi) >> 1; if (batch[mid] < g) lo = mid + 1; else hi = mid; }
    int start = lo;
    hi = n;
    while (lo < hi) { int mid = (lo + hi) >> 1; if (batch[mid] < g + 1) lo = mid + 1; else hi = mid; }
    int end = lo;

    float acc = 0.0f;
    for (int nd = start; nd < end; ++nd) acc += H[(size_t)nd * NFEAT + tid];
    float cnt = (float)((end - start) > 0 ? (end - start) : 1);
    float v = (acc / cnt) * Wfc[tid];

    __shared__ float red[128];
    red[tid] = v;
    __syncthreads();
    #pragma unroll
    for (int s = 64; s > 0; s >>= 1) {
        if (tid < s) red[tid] += red[tid + s];
        __syncthreads();
    }
    if (tid == 0) out[g] = red[0] + bfc[0];
}

// ===========================================================================
// Host launcher
// ===========================================================================
template <typename IdxT, typename IdxV>
static void run_csr_path(const float* x, const int* ei, const int* batch,
                         const float* W1, const float* b1, const float* W2,
                         const float* b2, const float* Wfc, const float* bfc,
                         float* out, void* d_ws, hipStream_t stream) {
    char* ws = (char*)d_ws;
    const size_t fbytes = (size_t)(N_NODES + 1) * NFEAT * sizeof(float);  // +1 sentinel row
    float* hbuf   = (float*)ws;
    float* obuf   = (float*)(ws + fbytes);
    IdxT*  csr    = (IdxT*)(ws + 2 * fbytes);
    char*  p      = ws + 2 * fbytes + ((size_t)EPAD_MAX * sizeof(IdxT) + 15) / 16 * 16;
    int*   rowptr = (int*)p;                         p += ((size_t)(N_NODES + 1) * 4 + 15) / 16 * 16;
    float* dinv   = (float*)p;                       p += ((size_t)N_NODES * 4 + 15) / 16 * 16;
    int*   gcnt   = (int*)p;                         // 512 ints

    // scratch overlapping obuf (dead until gather1 writes it)
    int* degcnt = (int*)obuf;
    int* cursor = (int*)obuf + N_NODES;
    int* bsums  = (int*)obuf + 2 * N_NODES;
    // nodedot overlaps obuf head (obuf dead after gemm2 reads it)
    float* nodedot = (float*)obuf;

    // ---- CSR build + norms + graph counts ----
    hipMemsetAsync(degcnt, 0, (size_t)N_NODES * sizeof(int), stream);
    hipMemsetAsync(gcnt, 0, (size_t)N_GRAPHS * sizeof(int), stream);
    edge_deg_int_kernel<<<N_EDGES / 256, 256, 0, stream>>>(ei, degcnt, N_EDGES);
    batch_hist_kernel<<<SCAN_NB, 256, 0, stream>>>(batch, gcnt, N_NODES);
    scan1_kernel<<<SCAN_NB, 256, 0, stream>>>(degcnt, rowptr, bsums, dinv, N_NODES);
    scan2_kernel<<<1, 256, 0, stream>>>(bsums, SCAN_NB);
    scan3_kernel<<<SCAN_NB, 256, 0, stream>>>(rowptr, bsums, cursor, degcnt, N_NODES);
    fill_kernel<IdxT><<<N_EDGES / 256, 256, 0, stream>>>(ei, cursor, csr, N_EDGES);
    pad_kernel<IdxT><<<SCAN_NB, 256, 0, stream>>>(rowptr, cursor, csr, N_NODES);
    out_init_kernel<<<2, 256, 0, stream>>>(out, bfc, N_GRAPHS);
    // zero the sentinel row of hbuf (persists through both layers)
    hipMemsetAsync(hbuf + (size_t)N_NODES * NFEAT, 0, NFEAT * sizeof(float), stream);

    // ---- layer 1 ----
    gemm64_kernel<<<(N_NODES / 64) * 2, 256, 0, stream>>>(x, W1, dinv, hbuf);
    gather_sliced_kernel<IdxT, IdxV, false><<<NSLICES * SLICE_BLOCKS, 256, 0, stream>>>(
        rowptr, csr, dinv, hbuf, b1, obuf, nullptr, nullptr);

    // ---- layer 2 ----
    gemm64_kernel<<<(N_NODES / 64) * 2, 256, 0, stream>>>(obuf, W2, dinv, hbuf);
    hipMemsetAsync(nodedot, 0, (size_t)N_NODES * sizeof(float), stream);  // obuf dead now
    gather_sliced_kernel<IdxT, IdxV, true><<<NSLICES * SLICE_BLOCKS, 256, 0, stream>>>(
        rowptr, csr, dinv, hbuf, b2, nullptr, Wfc, nodedot);

    // ---- final pool ----
    pool_final_kernel<<<SCAN_NB, 256, 0, stream>>>(nodedot, batch, gcnt, out, N_NODES);
}

extern "C" void kernel_launch(void* const* d_in, const int* in_sizes, int n_in,
                              void* d_out, int out_size, void* d_ws, size_t ws_size,
                              hipStream_t stream) {
    const float* x     = (const float*)d_in[0];
    const int*   ei    = (const int*)  d_in[1];
    const int*   batch = (const int*)  d_in[2];
    const float* W1    = (const float*)d_in[3];
    const float* b1    = (const float*)d_in[4];
    const float* W2    = (const float*)d_in[5];
    const float* b2    = (const float*)d_in[6];
    const float* Wfc   = (const float*)d_in[7];
    const float* bfc   = (const float*)d_in[8];
    float* out = (float*)d_out;

    const size_t fbytes = (size_t)(N_NODES + 1) * NFEAT * sizeof(float);
    const size_t tail   = ((size_t)(N_NODES + 1) * 4 + 15) / 16 * 16
                        + ((size_t)N_NODES * 4 + 15) / 16 * 16
                        + (size_t)N_GRAPHS * 4;
    const size_t needA = 2 * fbytes + ((size_t)EPAD_MAX * 4 + 15) / 16 * 16 + tail;
    const size_t needB = 2 * fbytes + ((size_t)EPAD_MAX * 2 + 15) / 16 * 16 + tail;

    if (ws_size >= needA) {
        run_csr_path<int, int4>(x, ei, batch, W1, b1, W2, b2, Wfc, bfc, out, d_ws, stream);
    } else if (ws_size >= needB) {
        run_csr_path<unsigned short, ushort4>(x, ei, batch, W1, b1, W2, b2, Wfc, bfc, out, d_ws, stream);
    } else {
        // Tier C: atomic-scatter fallback
        float* ws   = (float*)d_ws;
        int*   degc = (int*)ws;
        float* dinv = ws + N_NODES;
        float* hbuf = ws + 2 * N_NODES;
        float* agg  = hbuf + (size_t)N_NODES * NFEAT;
        const size_t fb2 = (size_t)N_NODES * NFEAT * sizeof(float);

        hipMemsetAsync(degc, 0, (size_t)N_NODES * sizeof(int), stream);
        edge_deg_int_kernel<<<N_EDGES / 256, 256, 0, stream>>>(ei, degc, N_EDGES);
        dinv_from_int_kernel<<<SCAN_NB, 256, 0, stream>>>(degc, dinv, N_NODES);

        hipMemsetAsync(agg, 0, fb2, stream);
        gemm64_kernel<<<(N_NODES / 64) * 2, 256, 0, stream>>>(x, W1, dinv, hbuf);
        edge_scatter_kernel<<<(N_EDGES * 32) / 256, 256, 0, stream>>>(ei, dinv, hbuf, agg, N_EDGES);
        post_kernel<<<(N_NODES * 32) / 256, 256, 0, stream>>>(agg, hbuf, dinv, b1, N_NODES);

        gemm64_kernel<<<(N_NODES / 64) * 2, 256, 0, stream>>>(agg, W2, dinv, hbuf);
        hipMemsetAsync(agg, 0, fb2, stream);
        edge_scatter_kernel<<<(N_EDGES * 32) / 256, 256, 0, stream>>>(ei, dinv, hbuf, agg, N_EDGES);
        post_kernel<<<(N_NODES * 32) / 256, 256, 0, stream>>>(agg, hbuf, dinv, b2, N_NODES);

        pool_fc_kernel<<<N_GRAPHS, 128, 0, stream>>>(agg, batch, Wfc, bfc, out, N_NODES);
    }
}

// Round 5
// 324.474 us; speedup vs baseline: 1.2261x; 1.2261x over previous
//
#include <hip/hip_runtime.h>
#include <hip/hip_fp16.h>

#define N_NODES 40000
#define N_EDGES 640000
#define NFEAT   128
#define N_GRAPHS 512
#define SCAN_NB 157        // ceil(40000/256)
#define EPAD_MAX (N_EDGES + 3 * N_NODES)   // worst-case padded CSR

// ===========================================================================
// CSR build kernels (lists padded to multiple-of-4, sentinel row = N_NODES)
// ===========================================================================

__global__ void edge_deg_int_kernel(const int* __restrict__ ei, int* __restrict__ degcnt, int E) {
    int e = blockIdx.x * blockDim.x + threadIdx.x;
    if (e < E) atomicAdd(&degcnt[ei[E + e]], 1);
}

__global__ void batch_hist_kernel(const int* __restrict__ batch, int* __restrict__ gcnt, int n) {
    int i = blockIdx.x * blockDim.x + threadIdx.x;
    if (i < n) atomicAdd(&gcnt[batch[i]], 1);
}

// tier C helper
__global__ void dinv_from_int_kernel(const int* __restrict__ degcnt, float* __restrict__ dinv, int n) {
    int i = blockIdx.x * blockDim.x + threadIdx.x;
    if (i < n) dinv[i] = rsqrtf(1.0f + (float)degcnt[i]);
}

// scan PADDED degrees ((deg+3)&~3); also emit dinv = rsqrt(1+deg)
__global__ void scan1_kernel(const int* __restrict__ in, int* __restrict__ out,
                             int* __restrict__ bsums, float* __restrict__ dinv, int n) {
    __shared__ int tmp[256];
    int t = threadIdx.x;
    int i = blockIdx.x * 256 + t;
    int deg = (i < n) ? in[i] : 0;
    if (i < n) dinv[i] = rsqrtf(1.0f + (float)deg);
    int vp = (i < n) ? ((deg + 3) & ~3) : 0;
    tmp[t] = vp;
    __syncthreads();
    for (int off = 1; off < 256; off <<= 1) {
        int add = (t >= off) ? tmp[t - off] : 0;
        __syncthreads();
        tmp[t] += add;
        __syncthreads();
    }
    if (i < n) out[i] = tmp[t] - vp;
    if (t == 255) bsums[blockIdx.x] = tmp[255];
}

__global__ void scan2_kernel(int* __restrict__ bsums, int nb) {
    __shared__ int tmp[256];
    int t = threadIdx.x;
    int v = (t < nb) ? bsums[t] : 0;
    tmp[t] = v;
    __syncthreads();
    for (int off = 1; off < 256; off <<= 1) {
        int add = (t >= off) ? tmp[t - off] : 0;
        __syncthreads();
        tmp[t] += add;
        __syncthreads();
    }
    if (t < nb) bsums[t] = tmp[t] - v;
}

__global__ void scan3_kernel(int* __restrict__ rowptr, const int* __restrict__ bsums,
                             int* __restrict__ cursor, const int* __restrict__ degcnt,
                             int n) {
    int i = blockIdx.x * 256 + threadIdx.x;
    if (i < n) {
        int v = rowptr[i] + bsums[blockIdx.x];
        rowptr[i] = v;
        cursor[i] = v;
        if (i == n - 1) rowptr[n] = v + ((degcnt[i] + 3) & ~3);
    }
}

template <typename IdxT>
__global__ void fill_kernel(const int* __restrict__ ei, int* __restrict__ cursor,
                            IdxT* __restrict__ csr, int E) {
    int e = blockIdx.x * blockDim.x + threadIdx.x;
    if (e < E) {
        int c = ei[E + e];
        int p = atomicAdd(&cursor[c], 1);
        csr[p] = (IdxT)ei[e];
    }
}

template <typename IdxT>
__global__ void pad_kernel(const int* __restrict__ rowptr, const int* __restrict__ cursor,
                           IdxT* __restrict__ csr, int n) {
    int i = blockIdx.x * blockDim.x + threadIdx.x;
    if (i < n) {
        int end = rowptr[i + 1];
        for (int p = cursor[i]; p < end; ++p) csr[p] = (IdxT)N_NODES;
    }
}

__global__ void out_init_kernel(float* __restrict__ out, const float* __restrict__ bfc, int g) {
    int i = blockIdx.x * blockDim.x + threadIdx.x;
    if (i < g) out[i] = bfc[0];
}

// ===========================================================================
// GEMM: Ht[r][c] = dinv[r] * sum_k X[r][k] * W[k][c]
// 256 threads -> 64 rows x 64 cols; W col-half (32 KB LDS) -> 4 blocks/CU.
// OutT = __half (main path, halves gather bytes) or float (tier C).
// ===========================================================================
template <typename OutT>
__global__ __launch_bounds__(256, 4) void gemm64_kernel(const float* __restrict__ X,
                                                        const float* __restrict__ W,
                                                        const float* __restrict__ dinv,
                                                        OutT* __restrict__ H) {
    __shared__ float Ws[128 * 64];
    const int colhalf = blockIdx.x & 1;
    const int tile    = blockIdx.x >> 1;

    for (int i = threadIdx.x; i < 2048; i += 256) {
        int k   = i >> 4;
        int cc4 = (i & 15) * 4;
        *(float4*)(Ws + k * 64 + cc4) = *(const float4*)(W + k * 128 + colhalf * 64 + cc4);
    }
    __syncthreads();

    const int rg = threadIdx.x >> 4;
    const int cg = threadIdx.x & 15;
    const int row0 = tile * 64 + rg * 4;
    const float* x0 = X + (size_t)row0 * NFEAT;

    float acc[4][4] = {};
    float4 xc[4], xn[4];
    #pragma unroll
    for (int i = 0; i < 4; i++) xc[i] = *(const float4*)(x0 + (size_t)i * NFEAT);

    #pragma unroll 4
    for (int k = 0; k < 128; k += 4) {
        const int kn = (k + 4) & 127;
        #pragma unroll
        for (int i = 0; i < 4; i++) xn[i] = *(const float4*)(x0 + (size_t)i * NFEAT + kn);

        float4 wv[4];
        #pragma unroll
        for (int m = 0; m < 4; m++) wv[m] = *(const float4*)(Ws + (k + m) * 64 + cg * 4);

        #pragma unroll
        for (int i = 0; i < 4; i++) {
            const float xi[4] = {xc[i].x, xc[i].y, xc[i].z, xc[i].w};
            #pragma unroll
            for (int m = 0; m < 4; m++) {
                acc[i][0] += xi[m] * wv[m].x;
                acc[i][1] += xi[m] * wv[m].y;
                acc[i][2] += xi[m] * wv[m].z;
                acc[i][3] += xi[m] * wv[m].w;
            }
        }
        #pragma unroll
        for (int i = 0; i < 4; i++) xc[i] = xn[i];
    }

    #pragma unroll
    for (int i = 0; i < 4; i++) {
        float dr = dinv[row0 + i];
        float v0 = acc[i][0] * dr, v1 = acc[i][1] * dr;
        float v2 = acc[i][2] * dr, v3 = acc[i][3] * dr;
        size_t off = (size_t)(row0 + i) * NFEAT + colhalf * 64 + cg * 4;
        if constexpr (sizeof(OutT) == 2) {
            __half2 p0 = __floats2half2_rn(v0, v1);
            __half2 p1 = __floats2half2_rn(v2, v3);
            uint2 pk;
            pk.x = *(unsigned int*)&p0;
            pk.y = *(unsigned int*)&p1;
            *(uint2*)((__half*)H + off) = pk;
        } else {
            float4 o = {v0, v1, v2, v3};
            *(float4*)((float*)H + off) = o;
        }
    }
}

// ===========================================================================
// fp16 gather: out[c] = relu(dinv[c]*(sum_{r in N(c)} Ht[r] + Ht[c]) + b)
// One wave per node; Ht row = 256 B fp16. Each lane covers 4 feats (8 B);
// 32 lanes span the row; half-waves take alternating neighbors so one VMEM
// instr covers 2 rows (512 B). Padded CSR -> aligned 4-index vector loads.
// FUSE_POOL: dot slice with Wfc, reduce, plain-store nodedot[node].
// ===========================================================================
__device__ inline float4 load_h4(const __half* p) {
    uint2 raw = *(const uint2*)p;
    __half2 h0 = *(__half2*)&raw.x;
    __half2 h1 = *(__half2*)&raw.y;
    float2 f0 = __half22float2(h0);
    float2 f1 = __half22float2(h1);
    return make_float4(f0.x, f0.y, f1.x, f1.y);
}

template <typename IdxT, typename IdxV, bool FUSE_POOL>
__global__ __launch_bounds__(256) void gather_h16_kernel(
        const int* __restrict__ rowptr, const IdxT* __restrict__ csr,
        const float* __restrict__ dinv, const __half* __restrict__ Ht,
        const float* __restrict__ bias, float* __restrict__ out,
        const float* __restrict__ Wfc, float* __restrict__ nodedot, int n) {
    int gid  = blockIdx.x * blockDim.x + threadIdx.x;
    int node = gid >> 6;
    if (node >= n) return;
    int lane = threadIdx.x & 63;
    int half = lane >> 5;
    int f4   = (lane & 31) * 4;

    int start = rowptr[node];
    int end   = rowptr[node + 1];

    float4 a0 = {0.f, 0.f, 0.f, 0.f};
    float4 a1 = {0.f, 0.f, 0.f, 0.f};
    if (half == 0) a0 = load_h4(Ht + (size_t)node * NFEAT + f4);  // self-loop

    for (int j = start; j < end; j += 4) {
        IdxV rr = *(const IdxV*)(csr + j);   // aligned: start % 4 == 0
        int r0 = half ? (int)rr.z : (int)rr.x;
        int r1 = half ? (int)rr.w : (int)rr.y;
        float4 v0 = load_h4(Ht + (size_t)r0 * NFEAT + f4);
        float4 v1 = load_h4(Ht + (size_t)r1 * NFEAT + f4);
        a0.x += v0.x; a0.y += v0.y; a0.z += v0.z; a0.w += v0.w;
        a1.x += v1.x; a1.y += v1.y; a1.z += v1.z; a1.w += v1.w;
    }
    a0.x += a1.x; a0.y += a1.y; a0.z += a1.z; a0.w += a1.w;

    // combine half-waves
    a0.x += __shfl_xor(a0.x, 32, 64);
    a0.y += __shfl_xor(a0.y, 32, 64);
    a0.z += __shfl_xor(a0.z, 32, 64);
    a0.w += __shfl_xor(a0.w, 32, 64);

    if (half == 0) {
        float di  = dinv[node];
        float4 bb = *(const float4*)(bias + f4);
        float4 o;
        o.x = fmaxf(a0.x * di + bb.x, 0.0f);
        o.y = fmaxf(a0.y * di + bb.y, 0.0f);
        o.z = fmaxf(a0.z * di + bb.z, 0.0f);
        o.w = fmaxf(a0.w * di + bb.w, 0.0f);
        if (!FUSE_POOL) {
            *(float4*)(out + (size_t)node * NFEAT + f4) = o;
        } else {
            float4 wf = *(const float4*)(Wfc + f4);
            float d = o.x * wf.x + o.y * wf.y + o.z * wf.z + o.w * wf.w;
            d += __shfl_xor(d, 1, 64);
            d += __shfl_xor(d, 2, 64);
            d += __shfl_xor(d, 4, 64);
            d += __shfl_xor(d, 8, 64);
            d += __shfl_xor(d, 16, 64);
            if (lane == 0) nodedot[node] = d;   // wave owns node: plain store
        }
    }
}

// out[batch[i]] += nodedot[i] / cnt
__global__ void pool_final_kernel(const float* __restrict__ nodedot,
                                  const int* __restrict__ batch,
                                  const int* __restrict__ gcnt,
                                  float* __restrict__ out, int n) {
    int i = blockIdx.x * blockDim.x + threadIdx.x;
    if (i < n) {
        int g = batch[i];
        int c = gcnt[g];
        float cf = (float)(c > 0 ? c : 1);
        atomicAdd(&out[g], nodedot[i] / cf);
    }
}

// ===========================================================================
// Tier C fallback kernels (fp32, atomic scatter)
// ===========================================================================
__global__ __launch_bounds__(256) void edge_scatter_kernel(const int* __restrict__ ei,
                                                           const float* __restrict__ dinv,
                                                           const float* __restrict__ H,
                                                           float* __restrict__ agg,
                                                           int E) {
    long long gid = (long long)blockIdx.x * blockDim.x + threadIdx.x;
    int e = (int)(gid >> 5);
    if (e >= E) return;
    int c4 = ((int)gid & 31) * 4;
    int r = ei[e];
    int c = ei[E + e];
    float norm = dinv[c];
    const float4 hv = *(const float4*)(H + (size_t)r * NFEAT + c4);
    float* dst = agg + (size_t)c * NFEAT + c4;
    atomicAdd(dst + 0, hv.x * norm);
    atomicAdd(dst + 1, hv.y * norm);
    atomicAdd(dst + 2, hv.z * norm);
    atomicAdd(dst + 3, hv.w * norm);
}

__global__ void post_kernel(float* __restrict__ agg, const float* __restrict__ H,
                            const float* __restrict__ dinv, const float* __restrict__ b,
                            int n) {
    int gid = blockIdx.x * blockDim.x + threadIdx.x;
    if (gid >= n * 32) return;
    int node = gid >> 5;
    int c4 = (gid & 31) * 4;
    float s = dinv[node];
    float4 a  = *(float4*)(agg + (size_t)gid * 4);
    float4 hv = *(const float4*)(H + (size_t)gid * 4);
    float4 bb = *(const float4*)(b + c4);
    float4 o;
    o.x = fmaxf(a.x + hv.x * s + bb.x, 0.0f);
    o.y = fmaxf(a.y + hv.y * s + bb.y, 0.0f);
    o.z = fmaxf(a.z + hv.z * s + bb.z, 0.0f);
    o.w = fmaxf(a.w + hv.w * s + bb.w, 0.0f);
    *(float4*)(agg + (size_t)gid * 4) = o;
}

__global__ __launch_bounds__(128) void pool_fc_kernel(const float* __restrict__ H,
                                                      const int* __restrict__ batch,
                                                      const float* __restrict__ Wfc,
                                                      const float* __restrict__ bfc,
                                                      float* __restrict__ out, int n) {
    int g = blockIdx.x;
    int tid = threadIdx.x;
    int lo = 0, hi = n;
    while (lo < hi) { int mid = (lo + hi) >> 1; if (batch[mid] < g) lo = mid + 1; else hi = mid; }
    int start = lo;
    hi = n;
    while (lo < hi) { int mid = (lo + hi) >> 1; if (batch[mid] < g + 1) lo = mid + 1; else hi = mid; }
    int end = lo;

    float acc = 0.0f;
    for (int nd = start; nd < end; ++nd) acc += H[(size_t)nd * NFEAT + tid];
    float cnt = (float)((end - start) > 0 ? (end - start) : 1);
    float v = (acc / cnt) * Wfc[tid];

    __shared__ float red[128];
    red[tid] = v;
    __syncthreads();
    #pragma unroll
    for (int s = 64; s > 0; s >>= 1) {
        if (tid < s) red[tid] += red[tid + s];
        __syncthreads();
    }
    if (tid == 0) out[g] = red[0] + bfc[0];
}

// ===========================================================================
// Host launcher
// ===========================================================================
template <typename IdxT, typename IdxV>
static void run_csr_path(const float* x, const int* ei, const int* batch,
                         const float* W1, const float* b1, const float* W2,
                         const float* b2, const float* Wfc, const float* bfc,
                         float* out, void* d_ws, hipStream_t stream) {
    char* ws = (char*)d_ws;
    const size_t hbytes = (size_t)(N_NODES + 1) * NFEAT * sizeof(__half);  // +1 sentinel row
    const size_t obytes = (size_t)N_NODES * NFEAT * sizeof(float);
    __half* hbuf  = (__half*)ws;
    float*  obuf  = (float*)(ws + hbytes);
    IdxT*   csr   = (IdxT*)(ws + hbytes + obytes);
    char*   p     = ws + hbytes + obytes + ((size_t)EPAD_MAX * sizeof(IdxT) + 15) / 16 * 16;
    int*    rowptr = (int*)p;                p += ((size_t)(N_NODES + 1) * 4 + 15) / 16 * 16;
    float*  dinv   = (float*)p;              p += ((size_t)N_NODES * 4 + 15) / 16 * 16;
    int*    gcnt   = (int*)p;                // 512 ints

    // scratch overlapping obuf (dead until gather1 writes it)
    int* degcnt = (int*)obuf;
    int* cursor = (int*)obuf + N_NODES;
    int* bsums  = (int*)obuf + 2 * N_NODES;
    // nodedot overlaps obuf head (obuf dead after gemm2 reads it; plain stores)
    float* nodedot = (float*)obuf;

    // ---- CSR build + norms + graph counts ----
    hipMemsetAsync(degcnt, 0, (size_t)N_NODES * sizeof(int), stream);
    hipMemsetAsync(gcnt, 0, (size_t)N_GRAPHS * sizeof(int), stream);
    edge_deg_int_kernel<<<N_EDGES / 256, 256, 0, stream>>>(ei, degcnt, N_EDGES);
    batch_hist_kernel<<<SCAN_NB, 256, 0, stream>>>(batch, gcnt, N_NODES);
    scan1_kernel<<<SCAN_NB, 256, 0, stream>>>(degcnt, rowptr, bsums, dinv, N_NODES);
    scan2_kernel<<<1, 256, 0, stream>>>(bsums, SCAN_NB);
    scan3_kernel<<<SCAN_NB, 256, 0, stream>>>(rowptr, bsums, cursor, degcnt, N_NODES);
    fill_kernel<IdxT><<<N_EDGES / 256, 256, 0, stream>>>(ei, cursor, csr, N_EDGES);
    pad_kernel<IdxT><<<SCAN_NB, 256, 0, stream>>>(rowptr, cursor, csr, N_NODES);
    out_init_kernel<<<2, 256, 0, stream>>>(out, bfc, N_GRAPHS);
    // zero sentinel row (persists through both layers)
    hipMemsetAsync(hbuf + (size_t)N_NODES * NFEAT, 0, NFEAT * sizeof(__half), stream);

    // ---- layer 1 ----
    gemm64_kernel<__half><<<(N_NODES / 64) * 2, 256, 0, stream>>>(x, W1, dinv, hbuf);
    gather_h16_kernel<IdxT, IdxV, false><<<(N_NODES * 64) / 256, 256, 0, stream>>>(
        rowptr, csr, dinv, hbuf, b1, obuf, nullptr, nullptr, N_NODES);

    // ---- layer 2 ----
    gemm64_kernel<__half><<<(N_NODES / 64) * 2, 256, 0, stream>>>(obuf, W2, dinv, hbuf);
    gather_h16_kernel<IdxT, IdxV, true><<<(N_NODES * 64) / 256, 256, 0, stream>>>(
        rowptr, csr, dinv, hbuf, b2, nullptr, Wfc, nodedot, N_NODES);

    // ---- final pool ----
    pool_final_kernel<<<SCAN_NB, 256, 0, stream>>>(nodedot, batch, gcnt, out, N_NODES);
}

extern "C" void kernel_launch(void* const* d_in, const int* in_sizes, int n_in,
                              void* d_out, int out_size, void* d_ws, size_t ws_size,
                              hipStream_t stream) {
    const float* x     = (const float*)d_in[0];
    const int*   ei    = (const int*)  d_in[1];
    const int*   batch = (const int*)  d_in[2];
    const float* W1    = (const float*)d_in[3];
    const float* b1    = (const float*)d_in[4];
    const float* W2    = (const float*)d_in[5];
    const float* b2    = (const float*)d_in[6];
    const float* Wfc   = (const float*)d_in[7];
    const float* bfc   = (const float*)d_in[8];
    float* out = (float*)d_out;

    const size_t hbytes = (size_t)(N_NODES + 1) * NFEAT * sizeof(__half);
    const size_t obytes = (size_t)N_NODES * NFEAT * sizeof(float);
    const size_t tail   = ((size_t)(N_NODES + 1) * 4 + 15) / 16 * 16
                        + ((size_t)N_NODES * 4 + 15) / 16 * 16
                        + (size_t)N_GRAPHS * 4;
    const size_t needA = hbytes + obytes + ((size_t)EPAD_MAX * 4 + 15) / 16 * 16 + tail;
    const size_t needB = hbytes + obytes + ((size_t)EPAD_MAX * 2 + 15) / 16 * 16 + tail;

    if (ws_size >= needA) {
        run_csr_path<int, int4>(x, ei, batch, W1, b1, W2, b2, Wfc, bfc, out, d_ws, stream);
    } else if (ws_size >= needB) {
        run_csr_path<unsigned short, ushort4>(x, ei, batch, W1, b1, W2, b2, Wfc, bfc, out, d_ws, stream);
    } else {
        // Tier C: fp32 atomic-scatter fallback
        float* ws   = (float*)d_ws;
        int*   degc = (int*)ws;
        float* dinv = ws + N_NODES;
        float* hbuf = ws + 2 * N_NODES;
        float* agg  = hbuf + (size_t)N_NODES * NFEAT;
        const size_t fb2 = (size_t)N_NODES * NFEAT * sizeof(float);

        hipMemsetAsync(degc, 0, (size_t)N_NODES * sizeof(int), stream);
        edge_deg_int_kernel<<<N_EDGES / 256, 256, 0, stream>>>(ei, degc, N_EDGES);
        dinv_from_int_kernel<<<SCAN_NB, 256, 0, stream>>>(degc, dinv, N_NODES);

        hipMemsetAsync(agg, 0, fb2, stream);
        gemm64_kernel<float><<<(N_NODES / 64) * 2, 256, 0, stream>>>(x, W1, dinv, hbuf);
        edge_scatter_kernel<<<(N_EDGES * 32) / 256, 256, 0, stream>>>(ei, dinv, hbuf, agg, N_EDGES);
        post_kernel<<<(N_NODES * 32) / 256, 256, 0, stream>>>(agg, hbuf, dinv, b1, N_NODES);

        gemm64_kernel<float><<<(N_NODES / 64) * 2, 256, 0, stream>>>(agg, W2, dinv, hbuf);
        hipMemsetAsync(agg, 0, fb2, stream);
        edge_scatter_kernel<<<(N_EDGES * 32) / 256, 256, 0, stream>>>(ei, dinv, hbuf, agg, N_EDGES);
        post_kernel<<<(N_NODES * 32) / 256, 256, 0, stream>>>(agg, hbuf, dinv, b2, N_NODES);

        pool_fc_kernel<<<N_GRAPHS, 128, 0, stream>>>(agg, batch, Wfc, bfc, out, N_NODES);
    }
}

// Round 6
// 285.773 us; speedup vs baseline: 1.3922x; 1.1354x over previous
//
#include <hip/hip_runtime.h>
#include <hip/hip_fp16.h>

#define N_NODES 40000
#define N_EDGES 640000
#define NFEAT   128
#define N_GRAPHS 512
#define SCAN_NB 157        // ceil(40000/256)
#define NBKT    157        // col buckets of 256 cols
#define BKT_CAP 8192       // slots per bucket region (mean 4096, 64-sigma safe)
#define BIN_BLK_EDGES 2048
#define NBLK_A ((N_EDGES + BIN_BLK_EDGES - 1) / BIN_BLK_EDGES)  // 313
#define EPAD_MAX (N_EDGES + 3 * N_NODES)   // worst-case padded CSR

// ===========================================================================
// Init (replaces all memsets): gcursor=0, gcnt=0, out=bfc, hbuf sentinel row=0
// ===========================================================================
__global__ void init_misc_kernel(int* __restrict__ gcursor, int* __restrict__ gcnt,
                                 float* __restrict__ out, const float* __restrict__ bfc,
                                 __half* __restrict__ hsent) {
    int t = threadIdx.x;
    if (t < NBKT) gcursor[t] = 0;
    float b = bfc[0];
    for (int i = t; i < N_GRAPHS; i += 256) { gcnt[i] = 0; out[i] = b; }
    if (t < NFEAT) hsent[t] = __float2half(0.0f);
}

__global__ void batch_hist_kernel(const int* __restrict__ batch, int* __restrict__ gcnt, int n) {
    int i = blockIdx.x * blockDim.x + threadIdx.x;
    if (i < n) atomicAdd(&gcnt[batch[i]], 1);
}

// ===========================================================================
// Pass A: bin edges into NBKT coarse buckets (col>>8), packed (collow<<16|row).
// LDS histogram -> one global cursor grab per bucket per block -> near-
// sequential writes into per-bucket regions (L2-friendly, no per-edge global
// atomic scatter).
// ===========================================================================
__global__ __launch_bounds__(256) void bin_kernel(const int* __restrict__ ei,
                                                  int* __restrict__ gcursor,
                                                  unsigned int* __restrict__ binned) {
    __shared__ int lhist[NBKT];
    __shared__ int lbase[NBKT];
    const int t  = threadIdx.x;
    const int e0 = blockIdx.x * BIN_BLK_EDGES;

    if (t < NBKT) lhist[t] = 0;
    __syncthreads();

    #pragma unroll
    for (int i = 0; i < BIN_BLK_EDGES / 256; ++i) {
        int e = e0 + i * 256 + t;
        if (e < N_EDGES) atomicAdd(&lhist[ei[N_EDGES + e] >> 8], 1);
    }
    __syncthreads();

    if (t < NBKT) { lbase[t] = atomicAdd(&gcursor[t], lhist[t]); lhist[t] = 0; }
    __syncthreads();

    #pragma unroll
    for (int i = 0; i < BIN_BLK_EDGES / 256; ++i) {
        int e = e0 + i * 256 + t;
        if (e < N_EDGES) {
            int c = ei[N_EDGES + e];
            int r = ei[e];
            int bkt = c >> 8;
            int slot = atomicAdd(&lhist[bkt], 1);
            binned[(size_t)bkt * BKT_CAP + lbase[bkt] + slot] =
                (unsigned int)r | ((unsigned int)(c & 255) << 16);
        }
    }
}

// ===========================================================================
// Pass B: per-bucket col histogram -> dinv + padded degree (replaces the
// random-atomic degree histogram).
// ===========================================================================
__global__ __launch_bounds__(256) void bucket_hist_kernel(const unsigned int* __restrict__ binned,
                                                          const int* __restrict__ gcursor,
                                                          float* __restrict__ dinv,
                                                          int* __restrict__ pdeg) {
    __shared__ int chist[256];
    const int b = blockIdx.x, t = threadIdx.x;
    chist[t] = 0;
    __syncthreads();
    const int cnt = gcursor[b];
    const unsigned int* src = binned + (size_t)b * BKT_CAP;
    for (int i = t; i < cnt; i += 256) atomicAdd(&chist[src[i] >> 16], 1);
    __syncthreads();
    int col = b * 256 + t;
    if (col < N_NODES) {
        int d = chist[t];
        dinv[col] = rsqrtf(1.0f + (float)d);
        pdeg[col] = (d + 3) & ~3;
    }
}

// ---- hierarchical exclusive scan over pdeg -> rowptr ----
__global__ void scan1_kernel(const int* __restrict__ in, int* __restrict__ out,
                             int* __restrict__ bsums, int n) {
    __shared__ int tmp[256];
    int t = threadIdx.x;
    int i = blockIdx.x * 256 + t;
    int v = (i < n) ? in[i] : 0;
    tmp[t] = v;
    __syncthreads();
    for (int off = 1; off < 256; off <<= 1) {
        int add = (t >= off) ? tmp[t - off] : 0;
        __syncthreads();
        tmp[t] += add;
        __syncthreads();
    }
    if (i < n) out[i] = tmp[t] - v;
    if (t == 255) bsums[blockIdx.x] = tmp[255];
}

__global__ void scan2_kernel(int* __restrict__ bsums, int nb) {
    __shared__ int tmp[256];
    int t = threadIdx.x;
    int v = (t < nb) ? bsums[t] : 0;
    tmp[t] = v;
    __syncthreads();
    for (int off = 1; off < 256; off <<= 1) {
        int add = (t >= off) ? tmp[t - off] : 0;
        __syncthreads();
        tmp[t] += add;
        __syncthreads();
    }
    if (t < nb) bsums[t] = tmp[t] - v;
}

__global__ void scan3_kernel(int* __restrict__ rowptr, const int* __restrict__ bsums,
                             const int* __restrict__ pdeg, int n) {
    int i = blockIdx.x * 256 + threadIdx.x;
    if (i < n) {
        int v = rowptr[i] + bsums[blockIdx.x];
        rowptr[i] = v;
        if (i == n - 1) rowptr[n] = v + pdeg[i];
    }
}

// ===========================================================================
// Pass C: per-bucket scatter into CSR via LDS cursors. All writes land in the
// bucket's contiguous rowptr range (L2-hot). Sentinel pads written here too.
// ===========================================================================
template <typename IdxT>
__global__ __launch_bounds__(256) void bucket_scatter_kernel(const unsigned int* __restrict__ binned,
                                                             const int* __restrict__ gcursor,
                                                             const int* __restrict__ rowptr,
                                                             IdxT* __restrict__ csr) {
    __shared__ int ccur[256];
    const int b = blockIdx.x, t = threadIdx.x;
    int col = b * 256 + t;
    ccur[t] = (col < N_NODES) ? rowptr[col] : 0;
    __syncthreads();
    const int cnt = gcursor[b];
    const unsigned int* src = binned + (size_t)b * BKT_CAP;
    for (int i = t; i < cnt; i += 256) {
        unsigned int u = src[i];
        int slot = atomicAdd(&ccur[u >> 16], 1);
        csr[slot] = (IdxT)(u & 0xFFFFu);
    }
    __syncthreads();
    if (col < N_NODES) {
        int end = rowptr[col + 1];
        for (int p = ccur[t]; p < end; ++p) csr[p] = (IdxT)N_NODES;
    }
}

// ===========================================================================
// GEMM: Ht[r][c] = dinv[r] * sum_k X[r][k] * W[k][c]
// 256 threads -> 64 rows x 64 cols; W col-half (32 KB LDS) -> 4 blocks/CU.
// ===========================================================================
template <typename OutT>
__global__ __launch_bounds__(256, 4) void gemm64_kernel(const float* __restrict__ X,
                                                        const float* __restrict__ W,
                                                        const float* __restrict__ dinv,
                                                        OutT* __restrict__ H) {
    __shared__ float Ws[128 * 64];
    const int colhalf = blockIdx.x & 1;
    const int tile    = blockIdx.x >> 1;

    for (int i = threadIdx.x; i < 2048; i += 256) {
        int k   = i >> 4;
        int cc4 = (i & 15) * 4;
        *(float4*)(Ws + k * 64 + cc4) = *(const float4*)(W + k * 128 + colhalf * 64 + cc4);
    }
    __syncthreads();

    const int rg = threadIdx.x >> 4;
    const int cg = threadIdx.x & 15;
    const int row0 = tile * 64 + rg * 4;
    const float* x0 = X + (size_t)row0 * NFEAT;

    float acc[4][4] = {};
    float4 xc[4], xn[4];
    #pragma unroll
    for (int i = 0; i < 4; i++) xc[i] = *(const float4*)(x0 + (size_t)i * NFEAT);

    #pragma unroll 4
    for (int k = 0; k < 128; k += 4) {
        const int kn = (k + 4) & 127;
        #pragma unroll
        for (int i = 0; i < 4; i++) xn[i] = *(const float4*)(x0 + (size_t)i * NFEAT + kn);

        float4 wv[4];
        #pragma unroll
        for (int m = 0; m < 4; m++) wv[m] = *(const float4*)(Ws + (k + m) * 64 + cg * 4);

        #pragma unroll
        for (int i = 0; i < 4; i++) {
            const float xi[4] = {xc[i].x, xc[i].y, xc[i].z, xc[i].w};
            #pragma unroll
            for (int m = 0; m < 4; m++) {
                acc[i][0] += xi[m] * wv[m].x;
                acc[i][1] += xi[m] * wv[m].y;
                acc[i][2] += xi[m] * wv[m].z;
                acc[i][3] += xi[m] * wv[m].w;
            }
        }
        #pragma unroll
        for (int i = 0; i < 4; i++) xc[i] = xn[i];
    }

    #pragma unroll
    for (int i = 0; i < 4; i++) {
        float dr = dinv[row0 + i];
        float v0 = acc[i][0] * dr, v1 = acc[i][1] * dr;
        float v2 = acc[i][2] * dr, v3 = acc[i][3] * dr;
        size_t off = (size_t)(row0 + i) * NFEAT + colhalf * 64 + cg * 4;
        if constexpr (sizeof(OutT) == 2) {
            __half2 p0 = __floats2half2_rn(v0, v1);
            __half2 p1 = __floats2half2_rn(v2, v3);
            uint2 pk;
            pk.x = *(unsigned int*)&p0;
            pk.y = *(unsigned int*)&p1;
            *(uint2*)((__half*)H + off) = pk;
        } else {
            float4 o = {v0, v1, v2, v3};
            *(float4*)((float*)H + off) = o;
        }
    }
}

// ===========================================================================
// fp16 gather: out[c] = relu(dinv[c]*(sum_{r in N(c)} Ht[r] + Ht[c]) + b)
// One wave per node; Ht row = 256 B fp16; half-waves take alternating
// neighbors (one VMEM instr covers 2 rows); padded CSR -> int4 index loads.
// FUSE_POOL: dot with Wfc, wave-reduce, plain store nodedot[node].
// ===========================================================================
__device__ inline float4 load_h4(const __half* p) {
    uint2 raw = *(const uint2*)p;
    __half2 h0 = *(__half2*)&raw.x;
    __half2 h1 = *(__half2*)&raw.y;
    float2 f0 = __half22float2(h0);
    float2 f1 = __half22float2(h1);
    return make_float4(f0.x, f0.y, f1.x, f1.y);
}

template <typename IdxT, typename IdxV, bool FUSE_POOL>
__global__ __launch_bounds__(256) void gather_h16_kernel(
        const int* __restrict__ rowptr, const IdxT* __restrict__ csr,
        const float* __restrict__ dinv, const __half* __restrict__ Ht,
        const float* __restrict__ bias, float* __restrict__ out,
        const float* __restrict__ Wfc, float* __restrict__ nodedot, int n) {
    int gid  = blockIdx.x * blockDim.x + threadIdx.x;
    int node = gid >> 6;
    if (node >= n) return;
    int lane = threadIdx.x & 63;
    int half = lane >> 5;
    int f4   = (lane & 31) * 4;

    int start = rowptr[node];
    int end   = rowptr[node + 1];

    float4 a0 = {0.f, 0.f, 0.f, 0.f};
    float4 a1 = {0.f, 0.f, 0.f, 0.f};
    if (half == 0) a0 = load_h4(Ht + (size_t)node * NFEAT + f4);  // self-loop

    for (int j = start; j < end; j += 4) {
        IdxV rr = *(const IdxV*)(csr + j);   // aligned: start % 4 == 0
        int r0 = half ? (int)rr.z : (int)rr.x;
        int r1 = half ? (int)rr.w : (int)rr.y;
        float4 v0 = load_h4(Ht + (size_t)r0 * NFEAT + f4);
        float4 v1 = load_h4(Ht + (size_t)r1 * NFEAT + f4);
        a0.x += v0.x; a0.y += v0.y; a0.z += v0.z; a0.w += v0.w;
        a1.x += v1.x; a1.y += v1.y; a1.z += v1.z; a1.w += v1.w;
    }
    a0.x += a1.x; a0.y += a1.y; a0.z += a1.z; a0.w += a1.w;

    a0.x += __shfl_xor(a0.x, 32, 64);
    a0.y += __shfl_xor(a0.y, 32, 64);
    a0.z += __shfl_xor(a0.z, 32, 64);
    a0.w += __shfl_xor(a0.w, 32, 64);

    if (half == 0) {
        float di  = dinv[node];
        float4 bb = *(const float4*)(bias + f4);
        float4 o;
        o.x = fmaxf(a0.x * di + bb.x, 0.0f);
        o.y = fmaxf(a0.y * di + bb.y, 0.0f);
        o.z = fmaxf(a0.z * di + bb.z, 0.0f);
        o.w = fmaxf(a0.w * di + bb.w, 0.0f);
        if (!FUSE_POOL) {
            *(float4*)(out + (size_t)node * NFEAT + f4) = o;
        } else {
            float4 wf = *(const float4*)(Wfc + f4);
            float d = o.x * wf.x + o.y * wf.y + o.z * wf.z + o.w * wf.w;
            d += __shfl_xor(d, 1, 64);
            d += __shfl_xor(d, 2, 64);
            d += __shfl_xor(d, 4, 64);
            d += __shfl_xor(d, 8, 64);
            d += __shfl_xor(d, 16, 64);
            if (lane == 0) nodedot[node] = d;   // wave owns node: plain store
        }
    }
}

// out[batch[i]] += nodedot[i] / cnt
__global__ void pool_final_kernel(const float* __restrict__ nodedot,
                                  const int* __restrict__ batch,
                                  const int* __restrict__ gcnt,
                                  float* __restrict__ out, int n) {
    int i = blockIdx.x * blockDim.x + threadIdx.x;
    if (i < n) {
        int g = batch[i];
        int c = gcnt[g];
        float cf = (float)(c > 0 ? c : 1);
        atomicAdd(&out[g], nodedot[i] / cf);
    }
}

// ===========================================================================
// Tier C fallback kernels (fp32, atomic scatter)
// ===========================================================================
__global__ void edge_deg_int_kernel(const int* __restrict__ ei, int* __restrict__ degcnt, int E) {
    int e = blockIdx.x * blockDim.x + threadIdx.x;
    if (e < E) atomicAdd(&degcnt[ei[E + e]], 1);
}

__global__ void dinv_from_int_kernel(const int* __restrict__ degcnt, float* __restrict__ dinv, int n) {
    int i = blockIdx.x * blockDim.x + threadIdx.x;
    if (i < n) dinv[i] = rsqrtf(1.0f + (float)degcnt[i]);
}

__global__ __launch_bounds__(256) void edge_scatter_kernel(const int* __restrict__ ei,
                                                           const float* __restrict__ dinv,
                                                           const float* __restrict__ H,
                                                           float* __restrict__ agg,
                                                           int E) {
    long long gid = (long long)blockIdx.x * blockDim.x + threadIdx.x;
    int e = (int)(gid >> 5);
    if (e >= E) return;
    int c4 = ((int)gid & 31) * 4;
    int r = ei[e];
    int c = ei[E + e];
    float norm = dinv[c];
    const float4 hv = *(const float4*)(H + (size_t)r * NFEAT + c4);
    float* dst = agg + (size_t)c * NFEAT + c4;
    atomicAdd(dst + 0, hv.x * norm);
    atomicAdd(dst + 1, hv.y * norm);
    atomicAdd(dst + 2, hv.z * norm);
    atomicAdd(dst + 3, hv.w * norm);
}

__global__ void post_kernel(float* __restrict__ agg, const float* __restrict__ H,
                            const float* __restrict__ dinv, const float* __restrict__ b,
                            int n) {
    int gid = blockIdx.x * blockDim.x + threadIdx.x;
    if (gid >= n * 32) return;
    int node = gid >> 5;
    int c4 = (gid & 31) * 4;
    float s = dinv[node];
    float4 a  = *(float4*)(agg + (size_t)gid * 4);
    float4 hv = *(const float4*)(H + (size_t)gid * 4);
    float4 bb = *(const float4*)(b + c4);
    float4 o;
    o.x = fmaxf(a.x + hv.x * s + bb.x, 0.0f);
    o.y = fmaxf(a.y + hv.y * s + bb.y, 0.0f);
    o.z = fmaxf(a.z + hv.z * s + bb.z, 0.0f);
    o.w = fmaxf(a.w + hv.w * s + bb.w, 0.0f);
    *(float4*)(agg + (size_t)gid * 4) = o;
}

__global__ __launch_bounds__(128) void pool_fc_kernel(const float* __restrict__ H,
                                                      const int* __restrict__ batch,
                                                      const float* __restrict__ Wfc,
                                                      const float* __restrict__ bfc,
                                                      float* __restrict__ out, int n) {
    int g = blockIdx.x;
    int tid = threadIdx.x;
    int lo = 0, hi = n;
    while (lo < hi) { int mid = (lo + hi) >> 1; if (batch[mid] < g) lo = mid + 1; else hi = mid; }
    int start = lo;
    hi = n;
    while (lo < hi) { int mid = (lo + hi) >> 1; if (batch[mid] < g + 1) lo = mid + 1; else hi = mid; }
    int end = lo;

    float acc = 0.0f;
    for (int nd = start; nd < end; ++nd) acc += H[(size_t)nd * NFEAT + tid];
    float cnt = (float)((end - start) > 0 ? (end - start) : 1);
    float v = (acc / cnt) * Wfc[tid];

    __shared__ float red[128];
    red[tid] = v;
    __syncthreads();
    #pragma unroll
    for (int s = 64; s > 0; s >>= 1) {
        if (tid < s) red[tid] += red[tid + s];
        __syncthreads();
    }
    if (tid == 0) out[g] = red[0] + bfc[0];
}

// ===========================================================================
// Host launcher
// ===========================================================================
template <typename IdxT, typename IdxV>
static void run_csr_path(const float* x, const int* ei, const int* batch,
                         const float* W1, const float* b1, const float* W2,
                         const float* b2, const float* Wfc, const float* bfc,
                         float* out, void* d_ws, hipStream_t stream) {
    char* ws = (char*)d_ws;
    const size_t hbytes = (size_t)(N_NODES + 1) * NFEAT * sizeof(__half);  // +1 sentinel row
    const size_t obytes = (size_t)N_NODES * NFEAT * sizeof(float);
    __half* hbuf  = (__half*)ws;
    float*  obuf  = (float*)(ws + hbytes);
    IdxT*   csr   = (IdxT*)(ws + hbytes + obytes);
    char*   p     = ws + hbytes + obytes + ((size_t)EPAD_MAX * sizeof(IdxT) + 15) / 16 * 16;
    int*    rowptr = (int*)p;                p += ((size_t)(N_NODES + 1) * 4 + 15) / 16 * 16;
    float*  dinv   = (float*)p;              p += ((size_t)N_NODES * 4 + 15) / 16 * 16;
    int*    gcnt   = (int*)p;                // 512 ints

    // CSR-build scratch overlapping obuf (dead until gather1 writes it)
    unsigned int* binned = (unsigned int*)obuf;                 // NBKT*BKT_CAP u32 = 5.14 MB
    int* pdeg    = (int*)obuf + NBKT * BKT_CAP;                 // N ints
    int* bsums   = pdeg + N_NODES;                              // SCAN_NB ints
    int* gcursor = bsums + SCAN_NB;                             // NBKT ints
    // nodedot overlaps obuf head (obuf dead after gemm2 reads it; plain stores)
    float* nodedot = (float*)obuf;

    // ---- init + CSR build (binned counting sort) ----
    init_misc_kernel<<<1, 256, 0, stream>>>(gcursor, gcnt, out, bfc,
                                            hbuf + (size_t)N_NODES * NFEAT);
    batch_hist_kernel<<<SCAN_NB, 256, 0, stream>>>(batch, gcnt, N_NODES);
    bin_kernel<<<NBLK_A, 256, 0, stream>>>(ei, gcursor, binned);
    bucket_hist_kernel<<<NBKT, 256, 0, stream>>>(binned, gcursor, dinv, pdeg);
    scan1_kernel<<<SCAN_NB, 256, 0, stream>>>(pdeg, rowptr, bsums, N_NODES);
    scan2_kernel<<<1, 256, 0, stream>>>(bsums, SCAN_NB);
    scan3_kernel<<<SCAN_NB, 256, 0, stream>>>(rowptr, bsums, pdeg, N_NODES);
    bucket_scatter_kernel<IdxT><<<NBKT, 256, 0, stream>>>(binned, gcursor, rowptr, csr);

    // ---- layer 1 ----
    gemm64_kernel<__half><<<(N_NODES / 64) * 2, 256, 0, stream>>>(x, W1, dinv, hbuf);
    gather_h16_kernel<IdxT, IdxV, false><<<(N_NODES * 64) / 256, 256, 0, stream>>>(
        rowptr, csr, dinv, hbuf, b1, obuf, nullptr, nullptr, N_NODES);

    // ---- layer 2 ----
    gemm64_kernel<__half><<<(N_NODES / 64) * 2, 256, 0, stream>>>(obuf, W2, dinv, hbuf);
    gather_h16_kernel<IdxT, IdxV, true><<<(N_NODES * 64) / 256, 256, 0, stream>>>(
        rowptr, csr, dinv, hbuf, b2, nullptr, Wfc, nodedot, N_NODES);

    // ---- final pool ----
    pool_final_kernel<<<SCAN_NB, 256, 0, stream>>>(nodedot, batch, gcnt, out, N_NODES);
}

extern "C" void kernel_launch(void* const* d_in, const int* in_sizes, int n_in,
                              void* d_out, int out_size, void* d_ws, size_t ws_size,
                              hipStream_t stream) {
    const float* x     = (const float*)d_in[0];
    const int*   ei    = (const int*)  d_in[1];
    const int*   batch = (const int*)  d_in[2];
    const float* W1    = (const float*)d_in[3];
    const float* b1    = (const float*)d_in[4];
    const float* W2    = (const float*)d_in[5];
    const float* b2    = (const float*)d_in[6];
    const float* Wfc   = (const float*)d_in[7];
    const float* bfc   = (const float*)d_in[8];
    float* out = (float*)d_out;

    const size_t hbytes = (size_t)(N_NODES + 1) * NFEAT * sizeof(__half);
    const size_t obytes = (size_t)N_NODES * NFEAT * sizeof(float);
    const size_t tail   = ((size_t)(N_NODES + 1) * 4 + 15) / 16 * 16
                        + ((size_t)N_NODES * 4 + 15) / 16 * 16
                        + (size_t)N_GRAPHS * 4;
    const size_t needA = hbytes + obytes + ((size_t)EPAD_MAX * 4 + 15) / 16 * 16 + tail;
    const size_t needB = hbytes + obytes + ((size_t)EPAD_MAX * 2 + 15) / 16 * 16 + tail;

    if (ws_size >= needA) {
        run_csr_path<int, int4>(x, ei, batch, W1, b1, W2, b2, Wfc, bfc, out, d_ws, stream);
    } else if (ws_size >= needB) {
        run_csr_path<unsigned short, ushort4>(x, ei, batch, W1, b1, W2, b2, Wfc, bfc, out, d_ws, stream);
    } else {
        // Tier C: fp32 atomic-scatter fallback
        float* ws   = (float*)d_ws;
        int*   degc = (int*)ws;
        float* dinv = ws + N_NODES;
        float* hbuf = ws + 2 * N_NODES;
        float* agg  = hbuf + (size_t)N_NODES * NFEAT;
        const size_t fb2 = (size_t)N_NODES * NFEAT * sizeof(float);

        hipMemsetAsync(degc, 0, (size_t)N_NODES * sizeof(int), stream);
        edge_deg_int_kernel<<<N_EDGES / 256, 256, 0, stream>>>(ei, degc, N_EDGES);
        dinv_from_int_kernel<<<SCAN_NB, 256, 0, stream>>>(degc, dinv, N_NODES);

        hipMemsetAsync(agg, 0, fb2, stream);
        gemm64_kernel<float><<<(N_NODES / 64) * 2, 256, 0, stream>>>(x, W1, dinv, hbuf);
        edge_scatter_kernel<<<(N_EDGES * 32) / 256, 256, 0, stream>>>(ei, dinv, hbuf, agg, N_EDGES);
        post_kernel<<<(N_NODES * 32) / 256, 256, 0, stream>>>(agg, hbuf, dinv, b1, N_NODES);

        gemm64_kernel<float><<<(N_NODES / 64) * 2, 256, 0, stream>>>(agg, W2, dinv, hbuf);
        hipMemsetAsync(agg, 0, fb2, stream);
        edge_scatter_kernel<<<(N_EDGES * 32) / 256, 256, 0, stream>>>(ei, dinv, hbuf, agg, N_EDGES);
        post_kernel<<<(N_NODES * 32) / 256, 256, 0, stream>>>(agg, hbuf, dinv, b2, N_NODES);

        pool_fc_kernel<<<N_GRAPHS, 128, 0, stream>>>(agg, batch, Wfc, bfc, out, N_NODES);
    }
}